// Round 10
// baseline (432.678 us; speedup 1.0000x reference)
//
#include <hip/hip_runtime.h>
#include <math.h>

#define N_NODES 100000
#define N_EDGES 3200000
#define N_GRAPH 1000
#define RSTRIDE 96     // padded srcs row stride (Poisson(32); P(deg>96)~1e-18)
#define NBUCKET 391    // ceil(N_NODES/256); bucket = dst >> 8
#define NBLK_A 196     // ceil(N_EDGES/CHUNK)
#define CHUNK 16384    // edges per bin block
#define SCAP 80        // per-block per-bucket slice capacity (mean 42, sd 6.5)
#define BCAP 9216      // max edges per bucket in pass B (mean 8192, sd 90)

// =================== init: pool sums/cnts = 0 ===================
__global__ void init_kernel(float* __restrict__ sums) {
    int i = blockIdx.x*blockDim.x + threadIdx.x;
    if (i < N_GRAPH*33) sums[i] = 0.0f;   // sums[32000] + cnts[1000] contiguous
}

// =================== pass A: bin edges into block-private bucket slices ===================
__global__ __launch_bounds__(512) void bin_kernel(const int* __restrict__ ei,
                                                  unsigned* __restrict__ region,
                                                  int* __restrict__ bcount) {
    __shared__ unsigned sorted[CHUNK];       // 64 KB
    __shared__ int hist[NBUCKET];
    __shared__ int excl[NBUCKET];
    __shared__ int cursor[NBUCKET];
    __shared__ int scanbuf[512];
    const long e0 = (long)blockIdx.x * CHUNK;
    const int t = threadIdx.x;

    for (int i = t; i < NBUCKET; i += 512) hist[i] = 0;
    __syncthreads();
    for (int i = t; i < CHUNK; i += 512) {
        long e = e0 + i;
        if (e < N_EDGES) atomicAdd(&hist[ei[N_EDGES + e] >> 8], 1);
    }
    __syncthreads();
    scanbuf[t] = (t < NBUCKET) ? hist[t] : 0;
    __syncthreads();
    for (int off = 1; off < 512; off <<= 1) {
        int v = (t >= off) ? scanbuf[t - off] : 0;
        __syncthreads();
        scanbuf[t] += v;
        __syncthreads();
    }
    if (t < NBUCKET) {
        int ex = scanbuf[t] - hist[t];
        excl[t] = ex;
        cursor[t] = ex;
    }
    __syncthreads();
    for (int i = t; i < CHUNK; i += 512) {
        long e = e0 + i;
        if (e < N_EDGES) {
            int dst = ei[N_EDGES + e];
            int src = ei[e];
            int b = dst >> 8;
            int pos = atomicAdd(&cursor[b], 1);
            sorted[pos] = ((unsigned)(dst & 255) << 17) | (unsigned)src;
        }
    }
    __syncthreads();
    int wv = t >> 6, lane = t & 63;
    for (int b = wv; b < NBUCKET; b += 8) {
        int cb = hist[b]; if (cb > SCAP) cb = SCAP;
        int lb = excl[b];
        unsigned* dp = region + ((size_t)blockIdx.x * NBUCKET + b) * SCAP;
        for (int i = lane; i < cb; i += 64) dp[i] = sorted[lb + i];
        if (lane == 0) bcount[blockIdx.x * NBUCKET + b] = cb;
    }
}

// =================== pass B: per-bucket CSR build in LDS -> sorted padded rows ===================
__global__ __launch_bounds__(256) void csr_kernel(const unsigned* __restrict__ region,
                                                  const int* __restrict__ bcount,
                                                  int* __restrict__ srcs_pad,
                                                  int* __restrict__ cnt) {
    __shared__ unsigned csr[BCAP];           // 36 KB
    __shared__ int hist[256];
    __shared__ int excl[256];
    __shared__ int cursor[256];
    __shared__ int blen[NBLK_A];
    const int b = blockIdx.x;
    const int t = threadIdx.x;

    for (int i = t; i < NBLK_A; i += 256) blen[i] = bcount[i * NBUCKET + b];
    hist[t] = 0;
    __syncthreads();
    for (int idx = t; idx < NBLK_A * SCAP; idx += 256) {
        int blk = idx / SCAP, i = idx % SCAP;
        if (i < blen[blk])
            atomicAdd(&hist[region[((size_t)blk * NBUCKET + b) * SCAP + i] >> 17], 1);
    }
    __syncthreads();
    int v = hist[t];
    excl[t] = v;
    __syncthreads();
    for (int off = 1; off < 256; off <<= 1) {
        int u = (t >= off) ? excl[t - off] : 0;
        __syncthreads();
        excl[t] += u;
        __syncthreads();
    }
    int incl = excl[t];
    __syncthreads();
    excl[t] = incl - v;
    cursor[t] = incl - v;
    __syncthreads();
    for (int idx = t; idx < NBLK_A * SCAP; idx += 256) {
        int blk = idx / SCAP, i = idx % SCAP;
        if (i < blen[blk]) {
            unsigned pk = region[((size_t)blk * NBUCKET + b) * SCAP + i];
            int pos = atomicAdd(&cursor[pk >> 17], 1);
            if (pos < BCAP) csr[pos] = pk & 0x1FFFFu;
        }
    }
    __syncthreads();
    // sort each node's row ascending by src: the gather then touches src
    // quantiles in iteration order -> per-XCD-L2-resident working set.
    // (order change only permutes FP sums -> rounding-level difference.)
    {
        int deg = hist[t]; if (deg > RSTRIDE) deg = RSTRIDE;
        int bs = excl[t];
        int end = bs + deg; if (end > BCAP) end = BCAP;
        for (int a = bs + 1; a < end; ++a) {
            unsigned key = csr[a];
            int p = a - 1;
            while (p >= bs && csr[p] > key) { csr[p+1] = csr[p]; --p; }
            csr[p+1] = key;
        }
    }
    __syncthreads();
    int wv = t >> 6, lane = t & 63;
    for (int i = wv; i < 256; i += 4) {
        int node = b * 256 + i;
        if (node >= N_NODES) continue;
        int deg = hist[i]; if (deg > RSTRIDE) deg = RSTRIDE;
        int bs = excl[i];
        for (int l = lane; l < deg; l += 64)
            if (bs + l < BCAP)
                srcs_pad[(size_t)node * RSTRIDE + l] = (int)csr[bs + l];
        if (lane == 0) cnt[node] = deg;
    }
}

// =================== node linears: qs (pre-scaled f32), kvb (bf16 k|v), skip ===================
__device__ __forceinline__ unsigned pack_bf16(float k, float v) {
    return ((__float_as_uint(k) + 0x8000u) >> 16) |
           ((__float_as_uint(v) + 0x8000u) & 0xffff0000u);
}

template<int IN, int OUT>
__global__ void lin_qkvs_kernel(const float* __restrict__ x,
                                const float* __restrict__ Wq, const float* __restrict__ bq,
                                const float* __restrict__ Wk, const float* __restrict__ bk,
                                const float* __restrict__ Wv, const float* __restrict__ bv,
                                const float* __restrict__ Ws, const float* __restrict__ bs,
                                float* __restrict__ qs, unsigned* __restrict__ kvb,
                                float* __restrict__ s, float scale) {
    __shared__ float w[4][IN*OUT];
    __shared__ float bb[4][OUT];
    const float* Wsrc[4] = {Wq, Wk, Wv, Ws};
    const float* bsrc[4] = {bq, bk, bv, bs};
    for (int t = threadIdx.x; t < 4*IN*OUT; t += blockDim.x)
        w[t/(IN*OUT)][t%(IN*OUT)] = Wsrc[t/(IN*OUT)][t%(IN*OUT)];
    for (int t = threadIdx.x; t < 4*OUT; t += blockDim.x)
        bb[t/OUT][t%OUT] = bsrc[t/OUT][t%OUT];
    __syncthreads();
    int i = blockIdx.x*blockDim.x + threadIdx.x;
    if (i >= N_NODES) return;
    float xr[IN];
    #pragma unroll
    for (int r = 0; r < IN; ++r) xr[r] = x[(long)i*IN + r];
    #pragma unroll
    for (int c = 0; c < OUT; ++c) {
        float aq = bb[0][c], ak = bb[1][c], av = bb[2][c], as = bb[3][c];
        #pragma unroll
        for (int r = 0; r < IN; ++r) {
            float xv = xr[r];
            aq = fmaf(xv, w[0][r*OUT + c], aq);
            ak = fmaf(xv, w[1][r*OUT + c], ak);
            av = fmaf(xv, w[2][r*OUT + c], av);
            as = fmaf(xv, w[3][r*OUT + c], as);
        }
        qs[(long)i*OUT + c] = aq * scale;
        kvb[(long)i*OUT + c] = pack_bf16(ak, av);
        s[(long)i*OUT + c] = as;
    }
}

// =================== gather: one node per wave, D/4 lanes per edge, NO-MAX softmax ===================
template<int D>
__global__ __launch_bounds__(256) void attn_gather_nm(const int* __restrict__ srcs_pad,
                                                      const int* __restrict__ cnt,
                                                      const float* __restrict__ qs,
                                                      const unsigned* __restrict__ kvb,
                                                      const float* __restrict__ s,
                                                      float* __restrict__ h) {
    constexpr int GL = D / 4;    // lanes per edge-group
    constexpr int G  = 64 / GL;  // concurrent edges per wave
    constexpr int I0 = 64 / G;   // iterations covered by b0
    int n = blockIdx.x*(blockDim.x >> 6) + (threadIdx.x >> 6);
    if (n >= N_NODES) return;
    int lane = threadIdx.x & 63;
    int g = lane / GL;
    int t = lane % GL;

    float4 q4 = *reinterpret_cast<const float4*>(qs + (size_t)n*D + 4*t);
    int deg = cnt[n];
    int rs = n * RSTRIDE;
    int b0 = (lane < deg)      ? srcs_pad[rs + lane]      : 0;   // clamped batch load
    int b1 = (64 + lane < deg) ? srcs_pad[rs + 64 + lane] : 0;

    float l = 0.0f;
    float4 acc = make_float4(0.f, 0.f, 0.f, 0.f);
    int iters = (deg + G - 1) / G;
    int iters0 = iters < I0 ? iters : I0;

    #pragma unroll 2
    for (int i = 0; i < iters0; ++i) {
        int idx = i*G + g;
        int sn = __shfl(b0, idx, 64);
        uint4 pk = *reinterpret_cast<const uint4*>(kvb + (size_t)sn*D + 4*t);
        float kx = __uint_as_float(pk.x << 16), vx = __uint_as_float(pk.x & 0xffff0000u);
        float ky = __uint_as_float(pk.y << 16), vy = __uint_as_float(pk.y & 0xffff0000u);
        float kz = __uint_as_float(pk.z << 16), vz = __uint_as_float(pk.z & 0xffff0000u);
        float kw = __uint_as_float(pk.w << 16), vw = __uint_as_float(pk.w & 0xffff0000u);
        float sc = fmaf(q4.x, kx, fmaf(q4.y, ky, fmaf(q4.z, kz, q4.w * kw)));
        #pragma unroll
        for (int off = 1; off < GL; off <<= 1) sc += __shfl_xor(sc, off, 64);
        float w = (idx < deg) ? __expf(sc) : 0.0f;
        l += w;
        acc.x = fmaf(w, vx, acc.x);
        acc.y = fmaf(w, vy, acc.y);
        acc.z = fmaf(w, vz, acc.z);
        acc.w = fmaf(w, vw, acc.w);
    }
    for (int i = I0; i < iters; ++i) {
        int idx = i*G + g;
        int sn = __shfl(b1, idx - 64, 64);
        uint4 pk = *reinterpret_cast<const uint4*>(kvb + (size_t)sn*D + 4*t);
        float kx = __uint_as_float(pk.x << 16), vx = __uint_as_float(pk.x & 0xffff0000u);
        float ky = __uint_as_float(pk.y << 16), vy = __uint_as_float(pk.y & 0xffff0000u);
        float kz = __uint_as_float(pk.z << 16), vz = __uint_as_float(pk.z & 0xffff0000u);
        float kw = __uint_as_float(pk.w << 16), vw = __uint_as_float(pk.w & 0xffff0000u);
        float sc = fmaf(q4.x, kx, fmaf(q4.y, ky, fmaf(q4.z, kz, q4.w * kw)));
        #pragma unroll
        for (int off = 1; off < GL; off <<= 1) sc += __shfl_xor(sc, off, 64);
        float w = (idx < deg) ? __expf(sc) : 0.0f;
        l += w;
        acc.x = fmaf(w, vx, acc.x);
        acc.y = fmaf(w, vy, acc.y);
        acc.z = fmaf(w, vz, acc.z);
        acc.w = fmaf(w, vw, acc.w);
    }
    #pragma unroll
    for (int off = GL; off < 64; off <<= 1) {
        l     += __shfl_xor(l, off, 64);
        acc.x += __shfl_xor(acc.x, off, 64);
        acc.y += __shfl_xor(acc.y, off, 64);
        acc.z += __shfl_xor(acc.z, off, 64);
        acc.w += __shfl_xor(acc.w, off, 64);
    }
    if (g == 0) {
        float inv = (l > 0.0f) ? 1.0f / l : 0.0f;
        float4 s4 = *reinterpret_cast<const float4*>(s + (size_t)n*D + 4*t);
        float4 o;
        o.x = fmaxf(fmaf(acc.x, inv, s4.x), 0.0f);
        o.y = fmaxf(fmaf(acc.y, inv, s4.y), 0.0f);
        o.z = fmaxf(fmaf(acc.z, inv, s4.z), 0.0f);
        o.w = fmaxf(fmaf(acc.w, inv, s4.w), 0.0f);
        *reinterpret_cast<float4*>(h + (size_t)n*D + 4*t) = o;
    }
}

// =================== pool: sorted batch -> block LDS reduction ===================
__global__ void pool_kernel(const float* __restrict__ h2, const int* __restrict__ batch,
                            float* __restrict__ sums, float* __restrict__ cnts) {
    __shared__ float sd[256];
    int n0 = blockIdx.x * 8;
    int t = threadIdx.x;
    int n = n0 + (t >> 5);
    int c = t & 31;
    int b = batch[n];
    float v = h2[(long)n*32 + c];
    int bfirst = batch[n0];
    int blast = batch[n0 + 7];
    if (bfirst == blast) {
        sd[t] = v;
        __syncthreads();
        if (t < 128) sd[t] += sd[t + 128];
        __syncthreads();
        if (t < 64) sd[t] += sd[t + 64];
        __syncthreads();
        if (t < 32) atomicAdd(&sums[bfirst*32 + t], sd[t] + sd[t + 32]);
        if (t == 0) atomicAdd(&cnts[bfirst], 8.0f);
    } else {
        atomicAdd(&sums[b*32 + c], v);
        if (c == 0) atomicAdd(&cnts[b], 1.0f);
    }
}

// =================== head MLP ===================
__global__ void head_kernel(const float* __restrict__ sums, const float* __restrict__ cnts,
                            const float* __restrict__ Wf1, const float* __restrict__ bf1,
                            const float* __restrict__ Wf2, const float* __restrict__ bf2,
                            float* __restrict__ out) {
    __shared__ float w1[32*64];
    __shared__ float b1[64];
    __shared__ float w2[64*2];
    __shared__ float b2[2];
    for (int t = threadIdx.x; t < 32*64; t += blockDim.x) w1[t] = Wf1[t];
    for (int t = threadIdx.x; t < 64; t += blockDim.x) b1[t] = bf1[t];
    for (int t = threadIdx.x; t < 128; t += blockDim.x) w2[t] = Wf2[t];
    if (threadIdx.x < 2) b2[threadIdx.x] = bf2[threadIdx.x];
    __syncthreads();
    int b = blockIdx.x*blockDim.x + threadIdx.x;
    if (b >= N_GRAPH) return;
    float inv = 1.0f / fmaxf(cnts[b], 1.0f);
    float pooled[32];
    #pragma unroll
    for (int c = 0; c < 32; ++c) pooled[c] = sums[b*32 + c] * inv;
    float z0 = b2[0], z1 = b2[1];
    for (int o = 0; o < 64; ++o) {
        float acc = b1[o];
        #pragma unroll
        for (int c = 0; c < 32; ++c) acc = fmaf(pooled[c], w1[c*64 + o], acc);
        acc = fmaxf(acc, 0.0f);
        z0 = fmaf(acc, w2[o*2 + 0], z0);
        z1 = fmaf(acc, w2[o*2 + 1], z1);
    }
    out[b*2 + 0] = 1.0f / (1.0f + __expf(-z0));
    out[b*2 + 1] = 1.0f / (1.0f + __expf(-z1));
}

extern "C" void kernel_launch(void* const* d_in, const int* in_sizes, int n_in,
                              void* d_out, int out_size, void* d_ws, size_t ws_size,
                              hipStream_t stream) {
    const float* x    = (const float*)d_in[0];
    const int*   ei   = (const int*)d_in[1];
    const int*   batch= (const int*)d_in[2];
    const float* Wq1 = (const float*)d_in[3],  *bq1 = (const float*)d_in[4];
    const float* Wk1 = (const float*)d_in[5],  *bk1 = (const float*)d_in[6];
    const float* Wv1 = (const float*)d_in[7],  *bv1 = (const float*)d_in[8];
    const float* Ws1 = (const float*)d_in[9],  *bs1 = (const float*)d_in[10];
    const float* Wq2 = (const float*)d_in[11], *bq2 = (const float*)d_in[12];
    const float* Wk2 = (const float*)d_in[13], *bk2 = (const float*)d_in[14];
    const float* Wv2 = (const float*)d_in[15], *bv2 = (const float*)d_in[16];
    const float* Ws2 = (const float*)d_in[17], *bs2 = (const float*)d_in[18];
    const float* Wf1 = (const float*)d_in[19], *bf1 = (const float*)d_in[20];
    const float* Wf2 = (const float*)d_in[21], *bf2 = (const float*)d_in[22];
    float* out = (float*)d_out;

    // ---- workspace layout, ~90.4 MB ----
    char* wsb = (char*)d_ws;
    int*      srcs_pad = (int*)wsb;                              // 38.4 MB
    int*      cnt      = srcs_pad + N_NODES*RSTRIDE + 256;       // 0.4 MB
    int*      bcount   = cnt + N_NODES;                          // 306 KB
    char*     regionA  = (char*)(bcount + NBLK_A*NBUCKET + 64);  // 25.6 MB
    unsigned* region   = (unsigned*)regionA;                     // 24.5 MB
    float*    qs       = (float*)regionA;                        // 12.8 MB
    unsigned* kvb      = (unsigned*)(qs + N_NODES*32);           // 12.8 MB
    float*    sB       = (float*)(regionA + (size_t)N_NODES*32*8); // 12.8 MB
    float*    hbuf     = sB + N_NODES*32;                        // 12.8 MB
    float*    sums     = hbuf + N_NODES*32;                      // 132 KB
    float*    cnts     = sums + N_GRAPH*32;

    float* h1 = hbuf;
    float* h2 = hbuf;

    const int B = 256;
    const float scale1 = 0.25f;
    const float scale2 = 0.17677669529663687f;

    // ---- index build: two-pass bucket sort (no global atomics) ----
    init_kernel<<<(N_GRAPH*33 + B-1)/B, B, 0, stream>>>(sums);
    bin_kernel<<<NBLK_A, 512, 0, stream>>>(ei, region, bcount);
    csr_kernel<<<NBUCKET, 256, 0, stream>>>(region, bcount, srcs_pad, cnt);

    // ---- layer 1 (d=16) ----
    lin_qkvs_kernel<9,16><<<(N_NODES + B-1)/B, B, 0, stream>>>(
        x, Wq1, bq1, Wk1, bk1, Wv1, bv1, Ws1, bs1, qs, kvb, sB, scale1);
    attn_gather_nm<16><<<(N_NODES + 3)/4, B, 0, stream>>>(
        srcs_pad, cnt, qs, kvb, sB, h1);

    // ---- layer 2 (d=32) ----
    lin_qkvs_kernel<16,32><<<(N_NODES + B-1)/B, B, 0, stream>>>(
        h1, Wq2, bq2, Wk2, bk2, Wv2, bv2, Ws2, bs2, qs, kvb, sB, scale2);
    attn_gather_nm<32><<<(N_NODES + 3)/4, B, 0, stream>>>(
        srcs_pad, cnt, qs, kvb, sB, h2);

    // ---- pool + head ----
    pool_kernel<<<N_NODES/8, B, 0, stream>>>(h2, batch, sums, cnts);
    head_kernel<<<(N_GRAPH + B-1)/B, B, 0, stream>>>(sums, cnts, Wf1, bf1, Wf2, bf2, out);
}

// Round 11
// 350.547 us; speedup vs baseline: 1.2343x; 1.2343x over previous
//
#include <hip/hip_runtime.h>
#include <math.h>

#define N_NODES 100000
#define N_EDGES 3200000
#define N_GRAPH 1000
#define RSTRIDE 96     // padded srcs row stride (Poisson(32); P(deg>96)~1e-18)
#define NBUCKET 391    // ceil(N_NODES/256); bucket = dst >> 8
#define NBLK_A 196     // ceil(N_EDGES/CHUNK)
#define CHUNK 16384    // edges per bin block
#define SCAP 80        // per-block per-bucket slice capacity (mean 42, sd 6.5)
#define BCAP 9216      // max edges per bucket in pass B (mean 8192, sd 90)

// =================== init: pool sums/cnts = 0 ===================
__global__ void init_kernel(float* __restrict__ sums) {
    int i = blockIdx.x*blockDim.x + threadIdx.x;
    if (i < N_GRAPH*33) sums[i] = 0.0f;   // sums[32000] + cnts[1000] contiguous
}

// =================== pass A: bin edges into block-private bucket slices ===================
__global__ __launch_bounds__(512) void bin_kernel(const int* __restrict__ ei,
                                                  unsigned* __restrict__ region,
                                                  int* __restrict__ bcount) {
    __shared__ unsigned sorted[CHUNK];       // 64 KB
    __shared__ int hist[NBUCKET];
    __shared__ int excl[NBUCKET];
    __shared__ int cursor[NBUCKET];
    __shared__ int scanbuf[512];
    const long e0 = (long)blockIdx.x * CHUNK;
    const int t = threadIdx.x;

    for (int i = t; i < NBUCKET; i += 512) hist[i] = 0;
    __syncthreads();
    for (int i = t; i < CHUNK; i += 512) {
        long e = e0 + i;
        if (e < N_EDGES) atomicAdd(&hist[ei[N_EDGES + e] >> 8], 1);
    }
    __syncthreads();
    scanbuf[t] = (t < NBUCKET) ? hist[t] : 0;
    __syncthreads();
    for (int off = 1; off < 512; off <<= 1) {
        int v = (t >= off) ? scanbuf[t - off] : 0;
        __syncthreads();
        scanbuf[t] += v;
        __syncthreads();
    }
    if (t < NBUCKET) {
        int ex = scanbuf[t] - hist[t];
        excl[t] = ex;
        cursor[t] = ex;
    }
    __syncthreads();
    for (int i = t; i < CHUNK; i += 512) {
        long e = e0 + i;
        if (e < N_EDGES) {
            int dst = ei[N_EDGES + e];
            int src = ei[e];
            int b = dst >> 8;
            int pos = atomicAdd(&cursor[b], 1);
            sorted[pos] = ((unsigned)(dst & 255) << 17) | (unsigned)src;
        }
    }
    __syncthreads();
    int wv = t >> 6, lane = t & 63;
    for (int b = wv; b < NBUCKET; b += 8) {
        int cb = hist[b]; if (cb > SCAP) cb = SCAP;
        int lb = excl[b];
        unsigned* dp = region + ((size_t)blockIdx.x * NBUCKET + b) * SCAP;
        for (int i = lane; i < cb; i += 64) dp[i] = sorted[lb + i];
        if (lane == 0) bcount[blockIdx.x * NBUCKET + b] = cb;
    }
}

// =================== pass B: per-bucket CSR build in LDS -> octant-grouped padded rows ===================
__global__ __launch_bounds__(256) void csr_kernel(const unsigned* __restrict__ region,
                                                  const int* __restrict__ bcount,
                                                  int* __restrict__ srcs_pad,
                                                  int* __restrict__ cnt) {
    __shared__ unsigned csr[BCAP];           // 36 KB
    __shared__ int hist[256];
    __shared__ int excl[256];
    __shared__ int cursor[256];
    __shared__ int blen[NBLK_A];
    const int b = blockIdx.x;
    const int t = threadIdx.x;

    for (int i = t; i < NBLK_A; i += 256) blen[i] = bcount[i * NBUCKET + b];
    hist[t] = 0;
    __syncthreads();
    for (int idx = t; idx < NBLK_A * SCAP; idx += 256) {
        int blk = idx / SCAP, i = idx % SCAP;
        if (i < blen[blk])
            atomicAdd(&hist[region[((size_t)blk * NBUCKET + b) * SCAP + i] >> 17], 1);
    }
    __syncthreads();
    int v = hist[t];
    excl[t] = v;
    __syncthreads();
    for (int off = 1; off < 256; off <<= 1) {
        int u = (t >= off) ? excl[t - off] : 0;
        __syncthreads();
        excl[t] += u;
        __syncthreads();
    }
    int incl = excl[t];
    __syncthreads();
    excl[t] = incl - v;
    cursor[t] = incl - v;
    __syncthreads();
    for (int idx = t; idx < NBLK_A * SCAP; idx += 256) {
        int blk = idx / SCAP, i = idx % SCAP;
        if (i < blen[blk]) {
            unsigned pk = region[((size_t)blk * NBUCKET + b) * SCAP + i];
            int pos = atomicAdd(&cursor[pk >> 17], 1);
            if (pos < BCAP) csr[pos] = pk & 0x1FFFFu;
        }
    }
    __syncthreads();
    // write-out with wave-parallel 7-way src-octant partition (src>>14):
    // grouped rows make concurrent gather iterations touch a ~2MB kvb slice
    // (L2-resident). Stable ballot+popc partition — no LDS, no serial sort.
    int wv = t >> 6, lane = t & 63;
    unsigned long long below = (1ULL << lane) - 1ULL;
    for (int i = wv; i < 256; i += 4) {
        int node = b * 256 + i;
        if (node >= N_NODES) continue;
        int deg = hist[i]; if (deg > RSTRIDE) deg = RSTRIDE;
        int bs = excl[i];
        unsigned v0 = (lane < deg && bs + lane < BCAP) ? csr[bs + lane] : 0xFFFFFFFFu;
        unsigned v1 = (64 + lane < deg && bs + 64 + lane < BCAP) ? csr[bs + 64 + lane] : 0xFFFFFFFFu;
        int o0 = v0 >> 14;    // 0..6 valid; huge for invalid slots
        int o1 = v1 >> 14;
        int off = 0;
        int* row = srcs_pad + (size_t)node * RSTRIDE;
        #pragma unroll
        for (int ob = 0; ob < 7; ++ob) {
            unsigned long long m0 = __ballot(o0 == ob);
            unsigned long long m1 = __ballot(o1 == ob);
            if (o0 == ob) row[off + __popcll(m0 & below)] = (int)v0;
            if (o1 == ob) row[off + __popcll(m0) + __popcll(m1 & below)] = (int)v1;
            off += __popcll(m0) + __popcll(m1);
        }
        if (lane == 0) cnt[node] = deg;
    }
}

// =================== node linears: qs (pre-scaled f32), kvb (bf16 k|v), skip ===================
__device__ __forceinline__ unsigned pack_bf16(float k, float v) {
    return ((__float_as_uint(k) + 0x8000u) >> 16) |
           ((__float_as_uint(v) + 0x8000u) & 0xffff0000u);
}

template<int IN, int OUT>
__global__ void lin_qkvs_kernel(const float* __restrict__ x,
                                const float* __restrict__ Wq, const float* __restrict__ bq,
                                const float* __restrict__ Wk, const float* __restrict__ bk,
                                const float* __restrict__ Wv, const float* __restrict__ bv,
                                const float* __restrict__ Ws, const float* __restrict__ bs,
                                float* __restrict__ qs, unsigned* __restrict__ kvb,
                                float* __restrict__ s, float scale) {
    __shared__ float w[4][IN*OUT];
    __shared__ float bb[4][OUT];
    const float* Wsrc[4] = {Wq, Wk, Wv, Ws};
    const float* bsrc[4] = {bq, bk, bv, bs};
    for (int t = threadIdx.x; t < 4*IN*OUT; t += blockDim.x)
        w[t/(IN*OUT)][t%(IN*OUT)] = Wsrc[t/(IN*OUT)][t%(IN*OUT)];
    for (int t = threadIdx.x; t < 4*OUT; t += blockDim.x)
        bb[t/OUT][t%OUT] = bsrc[t/OUT][t%OUT];
    __syncthreads();
    int i = blockIdx.x*blockDim.x + threadIdx.x;
    if (i >= N_NODES) return;
    float xr[IN];
    #pragma unroll
    for (int r = 0; r < IN; ++r) xr[r] = x[(long)i*IN + r];
    #pragma unroll
    for (int c = 0; c < OUT; ++c) {
        float aq = bb[0][c], ak = bb[1][c], av = bb[2][c], as = bb[3][c];
        #pragma unroll
        for (int r = 0; r < IN; ++r) {
            float xv = xr[r];
            aq = fmaf(xv, w[0][r*OUT + c], aq);
            ak = fmaf(xv, w[1][r*OUT + c], ak);
            av = fmaf(xv, w[2][r*OUT + c], av);
            as = fmaf(xv, w[3][r*OUT + c], as);
        }
        qs[(long)i*OUT + c] = aq * scale;
        kvb[(long)i*OUT + c] = pack_bf16(ak, av);
        s[(long)i*OUT + c] = as;
    }
}

// =================== gather: one node per wave, D/4 lanes per edge, NO-MAX softmax ===================
template<int D>
__global__ __launch_bounds__(256) void attn_gather_nm(const int* __restrict__ srcs_pad,
                                                      const int* __restrict__ cnt,
                                                      const float* __restrict__ qs,
                                                      const unsigned* __restrict__ kvb,
                                                      const float* __restrict__ s,
                                                      float* __restrict__ h) {
    constexpr int GL = D / 4;    // lanes per edge-group
    constexpr int G  = 64 / GL;  // concurrent edges per wave
    constexpr int I0 = 64 / G;   // iterations covered by b0
    int n = blockIdx.x*(blockDim.x >> 6) + (threadIdx.x >> 6);
    if (n >= N_NODES) return;
    int lane = threadIdx.x & 63;
    int g = lane / GL;
    int t = lane % GL;

    float4 q4 = *reinterpret_cast<const float4*>(qs + (size_t)n*D + 4*t);
    int deg = cnt[n];
    int rs = n * RSTRIDE;
    int b0 = (lane < deg)      ? srcs_pad[rs + lane]      : 0;   // clamped batch load
    int b1 = (64 + lane < deg) ? srcs_pad[rs + 64 + lane] : 0;

    float l = 0.0f;
    float4 acc = make_float4(0.f, 0.f, 0.f, 0.f);
    int iters = (deg + G - 1) / G;
    int iters0 = iters < I0 ? iters : I0;

    #pragma unroll 2
    for (int i = 0; i < iters0; ++i) {
        int idx = i*G + g;
        int sn = __shfl(b0, idx, 64);
        uint4 pk = *reinterpret_cast<const uint4*>(kvb + (size_t)sn*D + 4*t);
        float kx = __uint_as_float(pk.x << 16), vx = __uint_as_float(pk.x & 0xffff0000u);
        float ky = __uint_as_float(pk.y << 16), vy = __uint_as_float(pk.y & 0xffff0000u);
        float kz = __uint_as_float(pk.z << 16), vz = __uint_as_float(pk.z & 0xffff0000u);
        float kw = __uint_as_float(pk.w << 16), vw = __uint_as_float(pk.w & 0xffff0000u);
        float sc = fmaf(q4.x, kx, fmaf(q4.y, ky, fmaf(q4.z, kz, q4.w * kw)));
        #pragma unroll
        for (int off = 1; off < GL; off <<= 1) sc += __shfl_xor(sc, off, 64);
        float w = (idx < deg) ? __expf(sc) : 0.0f;
        l += w;
        acc.x = fmaf(w, vx, acc.x);
        acc.y = fmaf(w, vy, acc.y);
        acc.z = fmaf(w, vz, acc.z);
        acc.w = fmaf(w, vw, acc.w);
    }
    for (int i = I0; i < iters; ++i) {
        int idx = i*G + g;
        int sn = __shfl(b1, idx - 64, 64);
        uint4 pk = *reinterpret_cast<const uint4*>(kvb + (size_t)sn*D + 4*t);
        float kx = __uint_as_float(pk.x << 16), vx = __uint_as_float(pk.x & 0xffff0000u);
        float ky = __uint_as_float(pk.y << 16), vy = __uint_as_float(pk.y & 0xffff0000u);
        float kz = __uint_as_float(pk.z << 16), vz = __uint_as_float(pk.z & 0xffff0000u);
        float kw = __uint_as_float(pk.w << 16), vw = __uint_as_float(pk.w & 0xffff0000u);
        float sc = fmaf(q4.x, kx, fmaf(q4.y, ky, fmaf(q4.z, kz, q4.w * kw)));
        #pragma unroll
        for (int off = 1; off < GL; off <<= 1) sc += __shfl_xor(sc, off, 64);
        float w = (idx < deg) ? __expf(sc) : 0.0f;
        l += w;
        acc.x = fmaf(w, vx, acc.x);
        acc.y = fmaf(w, vy, acc.y);
        acc.z = fmaf(w, vz, acc.z);
        acc.w = fmaf(w, vw, acc.w);
    }
    #pragma unroll
    for (int off = GL; off < 64; off <<= 1) {
        l     += __shfl_xor(l, off, 64);
        acc.x += __shfl_xor(acc.x, off, 64);
        acc.y += __shfl_xor(acc.y, off, 64);
        acc.z += __shfl_xor(acc.z, off, 64);
        acc.w += __shfl_xor(acc.w, off, 64);
    }
    if (g == 0) {
        float inv = (l > 0.0f) ? 1.0f / l : 0.0f;
        float4 s4 = *reinterpret_cast<const float4*>(s + (size_t)n*D + 4*t);
        float4 o;
        o.x = fmaxf(fmaf(acc.x, inv, s4.x), 0.0f);
        o.y = fmaxf(fmaf(acc.y, inv, s4.y), 0.0f);
        o.z = fmaxf(fmaf(acc.z, inv, s4.z), 0.0f);
        o.w = fmaxf(fmaf(acc.w, inv, s4.w), 0.0f);
        *reinterpret_cast<float4*>(h + (size_t)n*D + 4*t) = o;
    }
}

// =================== pool: sorted batch -> block LDS reduction ===================
__global__ void pool_kernel(const float* __restrict__ h2, const int* __restrict__ batch,
                            float* __restrict__ sums, float* __restrict__ cnts) {
    __shared__ float sd[256];
    int n0 = blockIdx.x * 8;
    int t = threadIdx.x;
    int n = n0 + (t >> 5);
    int c = t & 31;
    int b = batch[n];
    float v = h2[(long)n*32 + c];
    int bfirst = batch[n0];
    int blast = batch[n0 + 7];
    if (bfirst == blast) {
        sd[t] = v;
        __syncthreads();
        if (t < 128) sd[t] += sd[t + 128];
        __syncthreads();
        if (t < 64) sd[t] += sd[t + 64];
        __syncthreads();
        if (t < 32) atomicAdd(&sums[bfirst*32 + t], sd[t] + sd[t + 32]);
        if (t == 0) atomicAdd(&cnts[bfirst], 8.0f);
    } else {
        atomicAdd(&sums[b*32 + c], v);
        if (c == 0) atomicAdd(&cnts[b], 1.0f);
    }
}

// =================== head MLP ===================
__global__ void head_kernel(const float* __restrict__ sums, const float* __restrict__ cnts,
                            const float* __restrict__ Wf1, const float* __restrict__ bf1,
                            const float* __restrict__ Wf2, const float* __restrict__ bf2,
                            float* __restrict__ out) {
    __shared__ float w1[32*64];
    __shared__ float b1[64];
    __shared__ float w2[64*2];
    __shared__ float b2[2];
    for (int t = threadIdx.x; t < 32*64; t += blockDim.x) w1[t] = Wf1[t];
    for (int t = threadIdx.x; t < 64; t += blockDim.x) b1[t] = bf1[t];
    for (int t = threadIdx.x; t < 128; t += blockDim.x) w2[t] = Wf2[t];
    if (threadIdx.x < 2) b2[threadIdx.x] = bf2[threadIdx.x];
    __syncthreads();
    int b = blockIdx.x*blockDim.x + threadIdx.x;
    if (b >= N_GRAPH) return;
    float inv = 1.0f / fmaxf(cnts[b], 1.0f);
    float pooled[32];
    #pragma unroll
    for (int c = 0; c < 32; ++c) pooled[c] = sums[b*32 + c] * inv;
    float z0 = b2[0], z1 = b2[1];
    for (int o = 0; o < 64; ++o) {
        float acc = b1[o];
        #pragma unroll
        for (int c = 0; c < 32; ++c) acc = fmaf(pooled[c], w1[c*64 + o], acc);
        acc = fmaxf(acc, 0.0f);
        z0 = fmaf(acc, w2[o*2 + 0], z0);
        z1 = fmaf(acc, w2[o*2 + 1], z1);
    }
    out[b*2 + 0] = 1.0f / (1.0f + __expf(-z0));
    out[b*2 + 1] = 1.0f / (1.0f + __expf(-z1));
}

extern "C" void kernel_launch(void* const* d_in, const int* in_sizes, int n_in,
                              void* d_out, int out_size, void* d_ws, size_t ws_size,
                              hipStream_t stream) {
    const float* x    = (const float*)d_in[0];
    const int*   ei   = (const int*)d_in[1];
    const int*   batch= (const int*)d_in[2];
    const float* Wq1 = (const float*)d_in[3],  *bq1 = (const float*)d_in[4];
    const float* Wk1 = (const float*)d_in[5],  *bk1 = (const float*)d_in[6];
    const float* Wv1 = (const float*)d_in[7],  *bv1 = (const float*)d_in[8];
    const float* Ws1 = (const float*)d_in[9],  *bs1 = (const float*)d_in[10];
    const float* Wq2 = (const float*)d_in[11], *bq2 = (const float*)d_in[12];
    const float* Wk2 = (const float*)d_in[13], *bk2 = (const float*)d_in[14];
    const float* Wv2 = (const float*)d_in[15], *bv2 = (const float*)d_in[16];
    const float* Ws2 = (const float*)d_in[17], *bs2 = (const float*)d_in[18];
    const float* Wf1 = (const float*)d_in[19], *bf1 = (const float*)d_in[20];
    const float* Wf2 = (const float*)d_in[21], *bf2 = (const float*)d_in[22];
    float* out = (float*)d_out;

    // ---- workspace layout, ~90.4 MB ----
    char* wsb = (char*)d_ws;
    int*      srcs_pad = (int*)wsb;                              // 38.4 MB
    int*      cnt      = srcs_pad + N_NODES*RSTRIDE + 256;       // 0.4 MB
    int*      bcount   = cnt + N_NODES;                          // 306 KB
    char*     regionA  = (char*)(bcount + NBLK_A*NBUCKET + 64);  // 25.6 MB
    unsigned* region   = (unsigned*)regionA;                     // 24.5 MB
    float*    qs       = (float*)regionA;                        // 12.8 MB
    unsigned* kvb      = (unsigned*)(qs + N_NODES*32);           // 12.8 MB
    float*    sB       = (float*)(regionA + (size_t)N_NODES*32*8); // 12.8 MB
    float*    hbuf     = sB + N_NODES*32;                        // 12.8 MB
    float*    sums     = hbuf + N_NODES*32;                      // 132 KB
    float*    cnts     = sums + N_GRAPH*32;

    float* h1 = hbuf;
    float* h2 = hbuf;

    const int B = 256;
    const float scale1 = 0.25f;
    const float scale2 = 0.17677669529663687f;

    // ---- index build: two-pass bucket sort (no global atomics) ----
    init_kernel<<<(N_GRAPH*33 + B-1)/B, B, 0, stream>>>(sums);
    bin_kernel<<<NBLK_A, 512, 0, stream>>>(ei, region, bcount);
    csr_kernel<<<NBUCKET, 256, 0, stream>>>(region, bcount, srcs_pad, cnt);

    // ---- layer 1 (d=16) ----
    lin_qkvs_kernel<9,16><<<(N_NODES + B-1)/B, B, 0, stream>>>(
        x, Wq1, bq1, Wk1, bk1, Wv1, bv1, Ws1, bs1, qs, kvb, sB, scale1);
    attn_gather_nm<16><<<(N_NODES + 3)/4, B, 0, stream>>>(
        srcs_pad, cnt, qs, kvb, sB, h1);

    // ---- layer 2 (d=32) ----
    lin_qkvs_kernel<16,32><<<(N_NODES + B-1)/B, B, 0, stream>>>(
        h1, Wq2, bq2, Wk2, bk2, Wv2, bv2, Ws2, bs2, qs, kvb, sB, scale2);
    attn_gather_nm<32><<<(N_NODES + 3)/4, B, 0, stream>>>(
        srcs_pad, cnt, qs, kvb, sB, h2);

    // ---- pool + head ----
    pool_kernel<<<N_NODES/8, B, 0, stream>>>(h2, batch, sums, cnts);
    head_kernel<<<(N_GRAPH + B-1)/B, B, 0, stream>>>(sums, cnts, Wf1, bf1, Wf2, bf2, out);
}

// Round 12
// 299.767 us; speedup vs baseline: 1.4434x; 1.1694x over previous
//
#include <hip/hip_runtime.h>
#include <math.h>

#define N_NODES 100000
#define N_EDGES 3200000
#define N_GRAPH 1000
#define RSTRIDE 96     // padded srcs row stride (Poisson(32); P(deg>96)~1e-18)
#define NBUCKET 391    // ceil(N_NODES/256); bucket = dst >> 8
#define NBLK_A 196     // ceil(N_EDGES/CHUNK)
#define CHUNK 16384    // edges per bin block
#define SCAP 80        // per-block per-bucket slice capacity (mean 42, sd 6.5; 5.9+ sd margin)
#define BCAP 9216      // max edges per bucket in pass B (mean 8192, sd 90)

// =================== init: pool sums/cnts = 0 ===================
__global__ void init_kernel(float* __restrict__ sums) {
    int i = blockIdx.x*blockDim.x + threadIdx.x;
    if (i < N_GRAPH*33) sums[i] = 0.0f;   // sums[32000] + cnts[1000] contiguous
}

// =================== pass A: bin edges into block-private bucket slices ===================
// No LDS sort: each block's region slices are a private ~125KB L2-resident
// window, so scattered 4B stores are line-merged by L2. One pass, tiny LDS.
__global__ __launch_bounds__(512) void bin_kernel(const int* __restrict__ ei,
                                                  unsigned* __restrict__ region,
                                                  int* __restrict__ bcount) {
    __shared__ int cursor[NBUCKET];
    const long e0 = (long)blockIdx.x * CHUNK;
    const int t = threadIdx.x;

    for (int i = t; i < NBUCKET; i += 512) cursor[i] = 0;
    __syncthreads();
    for (int i = t; i < CHUNK; i += 512) {
        long e = e0 + i;
        if (e < N_EDGES) {
            int dst = ei[N_EDGES + e];
            int src = ei[e];
            int b = dst >> 8;
            int pos = atomicAdd(&cursor[b], 1);
            if (pos < SCAP)
                region[((size_t)blockIdx.x * NBUCKET + b) * SCAP + pos] =
                    ((unsigned)(dst & 255) << 17) | (unsigned)src;
        }
    }
    __syncthreads();
    for (int i = t; i < NBUCKET; i += 512) {
        int c = cursor[i]; if (c > SCAP) c = SCAP;
        bcount[blockIdx.x * NBUCKET + i] = c;
    }
}

// =================== pass B: per-bucket CSR build in LDS -> padded rows (512 thr) ===================
__global__ __launch_bounds__(512) void csr_kernel(const unsigned* __restrict__ region,
                                                  const int* __restrict__ bcount,
                                                  int* __restrict__ srcs_pad,
                                                  int* __restrict__ cnt) {
    __shared__ unsigned csr[BCAP];           // 36 KB
    __shared__ int hist[256];
    __shared__ int excl[256];
    __shared__ int cursor[256];
    __shared__ int blen[NBLK_A];
    const int b = blockIdx.x;
    const int t = threadIdx.x;

    for (int i = t; i < NBLK_A; i += 512) blen[i] = bcount[i * NBUCKET + b];
    if (t < 256) hist[t] = 0;
    __syncthreads();
    for (int idx = t; idx < NBLK_A * SCAP; idx += 512) {
        int blk = idx / SCAP, i = idx % SCAP;   // const-divisor -> mulhi, no div
        if (i < blen[blk])
            atomicAdd(&hist[region[((size_t)blk * NBUCKET + b) * SCAP + i] >> 17], 1);
    }
    __syncthreads();
    int v = 0;
    if (t < 256) { v = hist[t]; excl[t] = v; }
    __syncthreads();
    for (int off = 1; off < 256; off <<= 1) {
        int u = (t < 256 && t >= off) ? excl[t - off] : 0;
        __syncthreads();
        if (t < 256) excl[t] += u;
        __syncthreads();
    }
    int incl = (t < 256) ? excl[t] : 0;
    __syncthreads();
    if (t < 256) { excl[t] = incl - v; cursor[t] = incl - v; }
    __syncthreads();
    for (int idx = t; idx < NBLK_A * SCAP; idx += 512) {
        int blk = idx / SCAP, i = idx % SCAP;
        if (i < blen[blk]) {
            unsigned pk = region[((size_t)blk * NBUCKET + b) * SCAP + i];
            int pos = atomicAdd(&cursor[pk >> 17], 1);
            if (pos < BCAP) csr[pos] = pk & 0x1FFFFu;
        }
    }
    __syncthreads();
    int wv = t >> 6, lane = t & 63;
    for (int i = wv; i < 256; i += 8) {
        int node = b * 256 + i;
        if (node >= N_NODES) continue;
        int deg = hist[i]; if (deg > RSTRIDE) deg = RSTRIDE;
        int bs = excl[i];
        for (int l = lane; l < deg; l += 64)
            if (bs + l < BCAP)
                srcs_pad[(size_t)node * RSTRIDE + l] = (int)csr[bs + l];
        if (lane == 0) cnt[node] = deg;
    }
}

// =================== node linears: qs (pre-scaled f32), kvb (bf16 k|v), skip ===================
__device__ __forceinline__ unsigned pack_bf16(float k, float v) {
    return ((__float_as_uint(k) + 0x8000u) >> 16) |
           ((__float_as_uint(v) + 0x8000u) & 0xffff0000u);
}

template<int IN, int OUT>
__global__ void lin_qkvs_kernel(const float* __restrict__ x,
                                const float* __restrict__ Wq, const float* __restrict__ bq,
                                const float* __restrict__ Wk, const float* __restrict__ bk,
                                const float* __restrict__ Wv, const float* __restrict__ bv,
                                const float* __restrict__ Ws, const float* __restrict__ bs,
                                float* __restrict__ qs, unsigned* __restrict__ kvb,
                                float* __restrict__ s, float scale) {
    __shared__ float w[4][IN*OUT];
    __shared__ float bb[4][OUT];
    const float* Wsrc[4] = {Wq, Wk, Wv, Ws};
    const float* bsrc[4] = {bq, bk, bv, bs};
    for (int t = threadIdx.x; t < 4*IN*OUT; t += blockDim.x)
        w[t/(IN*OUT)][t%(IN*OUT)] = Wsrc[t/(IN*OUT)][t%(IN*OUT)];
    for (int t = threadIdx.x; t < 4*OUT; t += blockDim.x)
        bb[t/OUT][t%OUT] = bsrc[t/OUT][t%OUT];
    __syncthreads();
    int i = blockIdx.x*blockDim.x + threadIdx.x;
    if (i >= N_NODES) return;
    float xr[IN];
    #pragma unroll
    for (int r = 0; r < IN; ++r) xr[r] = x[(long)i*IN + r];
    #pragma unroll
    for (int c = 0; c < OUT; ++c) {
        float aq = bb[0][c], ak = bb[1][c], av = bb[2][c], as = bb[3][c];
        #pragma unroll
        for (int r = 0; r < IN; ++r) {
            float xv = xr[r];
            aq = fmaf(xv, w[0][r*OUT + c], aq);
            ak = fmaf(xv, w[1][r*OUT + c], ak);
            av = fmaf(xv, w[2][r*OUT + c], av);
            as = fmaf(xv, w[3][r*OUT + c], as);
        }
        qs[(long)i*OUT + c] = aq * scale;
        kvb[(long)i*OUT + c] = pack_bf16(ak, av);
        s[(long)i*OUT + c] = as;
    }
}

// =================== gather: one node per wave, D/4 lanes per edge, NO-MAX softmax ===================
template<int D>
__global__ __launch_bounds__(256) void attn_gather_nm(const int* __restrict__ srcs_pad,
                                                      const int* __restrict__ cnt,
                                                      const float* __restrict__ qs,
                                                      const unsigned* __restrict__ kvb,
                                                      const float* __restrict__ s,
                                                      float* __restrict__ h) {
    constexpr int GL = D / 4;    // lanes per edge-group
    constexpr int G  = 64 / GL;  // concurrent edges per wave
    constexpr int I0 = 64 / G;   // iterations covered by b0
    int n = blockIdx.x*(blockDim.x >> 6) + (threadIdx.x >> 6);
    if (n >= N_NODES) return;
    int lane = threadIdx.x & 63;
    int g = lane / GL;
    int t = lane % GL;

    float4 q4 = *reinterpret_cast<const float4*>(qs + (size_t)n*D + 4*t);
    int deg = cnt[n];
    int rs = n * RSTRIDE;
    int b0 = (lane < deg)      ? srcs_pad[rs + lane]      : 0;   // clamped batch load
    int b1 = (64 + lane < deg) ? srcs_pad[rs + 64 + lane] : 0;

    float l = 0.0f;
    float4 acc = make_float4(0.f, 0.f, 0.f, 0.f);
    int iters = (deg + G - 1) / G;
    int iters0 = iters < I0 ? iters : I0;

    #pragma unroll 2
    for (int i = 0; i < iters0; ++i) {
        int idx = i*G + g;
        int sn = __shfl(b0, idx, 64);
        uint4 pk = *reinterpret_cast<const uint4*>(kvb + (size_t)sn*D + 4*t);
        float kx = __uint_as_float(pk.x << 16), vx = __uint_as_float(pk.x & 0xffff0000u);
        float ky = __uint_as_float(pk.y << 16), vy = __uint_as_float(pk.y & 0xffff0000u);
        float kz = __uint_as_float(pk.z << 16), vz = __uint_as_float(pk.z & 0xffff0000u);
        float kw = __uint_as_float(pk.w << 16), vw = __uint_as_float(pk.w & 0xffff0000u);
        float sc = fmaf(q4.x, kx, fmaf(q4.y, ky, fmaf(q4.z, kz, q4.w * kw)));
        #pragma unroll
        for (int off = 1; off < GL; off <<= 1) sc += __shfl_xor(sc, off, 64);
        float w = (idx < deg) ? __expf(sc) : 0.0f;
        l += w;
        acc.x = fmaf(w, vx, acc.x);
        acc.y = fmaf(w, vy, acc.y);
        acc.z = fmaf(w, vz, acc.z);
        acc.w = fmaf(w, vw, acc.w);
    }
    for (int i = I0; i < iters; ++i) {
        int idx = i*G + g;
        int sn = __shfl(b1, idx - 64, 64);
        uint4 pk = *reinterpret_cast<const uint4*>(kvb + (size_t)sn*D + 4*t);
        float kx = __uint_as_float(pk.x << 16), vx = __uint_as_float(pk.x & 0xffff0000u);
        float ky = __uint_as_float(pk.y << 16), vy = __uint_as_float(pk.y & 0xffff0000u);
        float kz = __uint_as_float(pk.z << 16), vz = __uint_as_float(pk.z & 0xffff0000u);
        float kw = __uint_as_float(pk.w << 16), vw = __uint_as_float(pk.w & 0xffff0000u);
        float sc = fmaf(q4.x, kx, fmaf(q4.y, ky, fmaf(q4.z, kz, q4.w * kw)));
        #pragma unroll
        for (int off = 1; off < GL; off <<= 1) sc += __shfl_xor(sc, off, 64);
        float w = (idx < deg) ? __expf(sc) : 0.0f;
        l += w;
        acc.x = fmaf(w, vx, acc.x);
        acc.y = fmaf(w, vy, acc.y);
        acc.z = fmaf(w, vz, acc.z);
        acc.w = fmaf(w, vw, acc.w);
    }
    #pragma unroll
    for (int off = GL; off < 64; off <<= 1) {
        l     += __shfl_xor(l, off, 64);
        acc.x += __shfl_xor(acc.x, off, 64);
        acc.y += __shfl_xor(acc.y, off, 64);
        acc.z += __shfl_xor(acc.z, off, 64);
        acc.w += __shfl_xor(acc.w, off, 64);
    }
    if (g == 0) {
        float inv = (l > 0.0f) ? 1.0f / l : 0.0f;
        float4 s4 = *reinterpret_cast<const float4*>(s + (size_t)n*D + 4*t);
        float4 o;
        o.x = fmaxf(fmaf(acc.x, inv, s4.x), 0.0f);
        o.y = fmaxf(fmaf(acc.y, inv, s4.y), 0.0f);
        o.z = fmaxf(fmaf(acc.z, inv, s4.z), 0.0f);
        o.w = fmaxf(fmaf(acc.w, inv, s4.w), 0.0f);
        *reinterpret_cast<float4*>(h + (size_t)n*D + 4*t) = o;
    }
}

// =================== pool: sorted batch -> block LDS reduction ===================
__global__ void pool_kernel(const float* __restrict__ h2, const int* __restrict__ batch,
                            float* __restrict__ sums, float* __restrict__ cnts) {
    __shared__ float sd[256];
    int n0 = blockIdx.x * 8;
    int t = threadIdx.x;
    int n = n0 + (t >> 5);
    int c = t & 31;
    int b = batch[n];
    float v = h2[(long)n*32 + c];
    int bfirst = batch[n0];
    int blast = batch[n0 + 7];
    if (bfirst == blast) {
        sd[t] = v;
        __syncthreads();
        if (t < 128) sd[t] += sd[t + 128];
        __syncthreads();
        if (t < 64) sd[t] += sd[t + 64];
        __syncthreads();
        if (t < 32) atomicAdd(&sums[bfirst*32 + t], sd[t] + sd[t + 32]);
        if (t == 0) atomicAdd(&cnts[bfirst], 8.0f);
    } else {
        atomicAdd(&sums[b*32 + c], v);
        if (c == 0) atomicAdd(&cnts[b], 1.0f);
    }
}

// =================== head MLP ===================
__global__ void head_kernel(const float* __restrict__ sums, const float* __restrict__ cnts,
                            const float* __restrict__ Wf1, const float* __restrict__ bf1,
                            const float* __restrict__ Wf2, const float* __restrict__ bf2,
                            float* __restrict__ out) {
    __shared__ float w1[32*64];
    __shared__ float b1[64];
    __shared__ float w2[64*2];
    __shared__ float b2[2];
    for (int t = threadIdx.x; t < 32*64; t += blockDim.x) w1[t] = Wf1[t];
    for (int t = threadIdx.x; t < 64; t += blockDim.x) b1[t] = bf1[t];
    for (int t = threadIdx.x; t < 128; t += blockDim.x) w2[t] = Wf2[t];
    if (threadIdx.x < 2) b2[threadIdx.x] = bf2[threadIdx.x];
    __syncthreads();
    int b = blockIdx.x*blockDim.x + threadIdx.x;
    if (b >= N_GRAPH) return;
    float inv = 1.0f / fmaxf(cnts[b], 1.0f);
    float pooled[32];
    #pragma unroll
    for (int c = 0; c < 32; ++c) pooled[c] = sums[b*32 + c] * inv;
    float z0 = b2[0], z1 = b2[1];
    for (int o = 0; o < 64; ++o) {
        float acc = b1[o];
        #pragma unroll
        for (int c = 0; c < 32; ++c) acc = fmaf(pooled[c], w1[c*64 + o], acc);
        acc = fmaxf(acc, 0.0f);
        z0 = fmaf(acc, w2[o*2 + 0], z0);
        z1 = fmaf(acc, w2[o*2 + 1], z1);
    }
    out[b*2 + 0] = 1.0f / (1.0f + __expf(-z0));
    out[b*2 + 1] = 1.0f / (1.0f + __expf(-z1));
}

extern "C" void kernel_launch(void* const* d_in, const int* in_sizes, int n_in,
                              void* d_out, int out_size, void* d_ws, size_t ws_size,
                              hipStream_t stream) {
    const float* x    = (const float*)d_in[0];
    const int*   ei   = (const int*)d_in[1];
    const int*   batch= (const int*)d_in[2];
    const float* Wq1 = (const float*)d_in[3],  *bq1 = (const float*)d_in[4];
    const float* Wk1 = (const float*)d_in[5],  *bk1 = (const float*)d_in[6];
    const float* Wv1 = (const float*)d_in[7],  *bv1 = (const float*)d_in[8];
    const float* Ws1 = (const float*)d_in[9],  *bs1 = (const float*)d_in[10];
    const float* Wq2 = (const float*)d_in[11], *bq2 = (const float*)d_in[12];
    const float* Wk2 = (const float*)d_in[13], *bk2 = (const float*)d_in[14];
    const float* Wv2 = (const float*)d_in[15], *bv2 = (const float*)d_in[16];
    const float* Ws2 = (const float*)d_in[17], *bs2 = (const float*)d_in[18];
    const float* Wf1 = (const float*)d_in[19], *bf1 = (const float*)d_in[20];
    const float* Wf2 = (const float*)d_in[21], *bf2 = (const float*)d_in[22];
    float* out = (float*)d_out;

    // ---- workspace layout, ~90.4 MB ----
    char* wsb = (char*)d_ws;
    int*      srcs_pad = (int*)wsb;                              // 38.4 MB
    int*      cnt      = srcs_pad + N_NODES*RSTRIDE + 256;       // 0.4 MB
    int*      bcount   = cnt + N_NODES;                          // 306 KB
    char*     regionA  = (char*)(bcount + NBLK_A*NBUCKET + 64);  // 25.6 MB
    unsigned* region   = (unsigned*)regionA;                     // 24.5 MB
    float*    qs       = (float*)regionA;                        // 12.8 MB
    unsigned* kvb      = (unsigned*)(qs + N_NODES*32);           // 12.8 MB
    float*    sB       = (float*)(regionA + (size_t)N_NODES*32*8); // 12.8 MB
    float*    hbuf     = sB + N_NODES*32;                        // 12.8 MB
    float*    sums     = hbuf + N_NODES*32;                      // 132 KB
    float*    cnts     = sums + N_GRAPH*32;

    float* h1 = hbuf;
    float* h2 = hbuf;

    const int B = 256;
    const float scale1 = 0.25f;
    const float scale2 = 0.17677669529663687f;

    // ---- index build: two-pass bucket sort (no global atomics) ----
    init_kernel<<<(N_GRAPH*33 + B-1)/B, B, 0, stream>>>(sums);
    bin_kernel<<<NBLK_A, 512, 0, stream>>>(ei, region, bcount);
    csr_kernel<<<NBUCKET, 512, 0, stream>>>(region, bcount, srcs_pad, cnt);

    // ---- layer 1 (d=16) ----
    lin_qkvs_kernel<9,16><<<(N_NODES + B-1)/B, B, 0, stream>>>(
        x, Wq1, bq1, Wk1, bk1, Wv1, bv1, Ws1, bs1, qs, kvb, sB, scale1);
    attn_gather_nm<16><<<(N_NODES + 3)/4, B, 0, stream>>>(
        srcs_pad, cnt, qs, kvb, sB, h1);

    // ---- layer 2 (d=32) ----
    lin_qkvs_kernel<16,32><<<(N_NODES + B-1)/B, B, 0, stream>>>(
        h1, Wq2, bq2, Wk2, bk2, Wv2, bv2, Ws2, bs2, qs, kvb, sB, scale2);
    attn_gather_nm<32><<<(N_NODES + 3)/4, B, 0, stream>>>(
        srcs_pad, cnt, qs, kvb, sB, h2);

    // ---- pool + head ----
    pool_kernel<<<N_NODES/8, B, 0, stream>>>(h2, batch, sums, cnts);
    head_kernel<<<(N_GRAPH + B-1)/B, B, 0, stream>>>(sums, cnts, Wf1, bf1, Wf2, bf2, out);
}